// Round 1
// baseline (2827.361 us; speedup 1.0000x reference)
//
#include <hip/hip_runtime.h>
#include <hip/hip_bf16.h>

// GRU_teach round 2: occupancy doubling + LDS-conflict fix.
// - RPB 16 -> 8, grid 256 -> 512 blocks => 2 independent blocks/CU
//   (declared LDS ~51 KB/block, __launch_bounds__(256,2) caps regs at 256).
//   MFMA tiles stay 16 rows (rows 8..15 zero-padded, C rows 8..15 discarded
//   via ln<32 store guards) -- MFMA pipe was 6% busy, waste is free.
// - OS out-window slot XOR-swizzle kills the 16-way bank conflicts
//   (d-stride was 32B = 8 banks; 64 lanes hit 4 banks on b16 ops).
// - h state lives in registers (hreg[4]) across the t-loop; LDS HF only
//   written once at the end for the classifier.

#define BSZ   4096
#define XD    128
#define YD    64
#define TT    200
#define NH3   300
#define RPB   8
#define NBLK  (BSZ / RPB)

typedef unsigned short u16;
typedef unsigned int   u32;
typedef __attribute__((ext_vector_type(8))) short s16x8;
typedef __attribute__((ext_vector_type(4))) float f32x4;

__device__ __forceinline__ float bf_lo(u32 u){ return __uint_as_float(u << 16); }
__device__ __forceinline__ float bf_hi(u32 u){ return __uint_as_float(u & 0xFFFF0000u); }
__device__ __forceinline__ u16 f2bf(float f){
  u32 u = __float_as_uint(f);
  u32 r = (u + 0x7FFFu + ((u >> 16) & 1u)) >> 16;   // RNE
  return (u16)r;
}
__device__ __forceinline__ float loadf(const void* p, size_t i, int fmode){
  return (fmode == 0) ? __uint_as_float(((u32)((const u16*)p)[i]) << 16)
                      : ((const float*)p)[i];
}
__device__ __forceinline__ float fsig(float x){ return 1.f/(1.f + __expf(-x)); }
__device__ __forceinline__ float ftanh(float x){ float e = __expf(2.f*x); return 1.f - 2.f/(e + 1.f); }

__device__ __forceinline__ f32x4 mfma16(uint4 a, uint4 b, f32x4 c){
  s16x8 as, bs;
  __builtin_memcpy(&as, &a, 16);
  __builtin_memcpy(&bs, &b, 16);
  return __builtin_amdgcn_mfma_f32_16x16x32_bf16(as, bs, c, 0, 0, 0);
}

// dot of fp32 LDS row (KB*8 floats, zero-padded) with k-blocked bf16 weights, column n of N
__device__ __forceinline__ float dotblk(const float* xr, const u16* wb, int n, int N, int KB){
  float a = 0.f;
  const uint4* wp = (const uint4*)wb;
  #pragma unroll
  for (int kb = 0; kb < KB; ++kb){
    uint4 u = wp[kb * N + n];
    const float4* xp = (const float4*)(xr + (kb << 3));
    float4 x0 = xp[0], x1 = xp[1];
    a += x0.x*bf_lo(u.x) + x0.y*bf_hi(u.x) + x0.z*bf_lo(u.y) + x0.w*bf_hi(u.y);
    a += x1.x*bf_lo(u.z) + x1.y*bf_hi(u.z) + x1.z*bf_lo(u.w) + x1.w*bf_hi(u.w);
  }
  return a;
}

// ---------------- dtype detection (unchanged, verified) ----------------
__global__ void detect_kernel(const void* mask, const void* x, int* flags){
  __shared__ int cnt[4];
  if (threadIdx.x < 4) cnt[threadIdx.x] = 0;
  __syncthreads();
  if (blockIdx.x == 0){
    const unsigned char* p = (const unsigned char*)mask;
    int c0=0, c1=0, c2=0, c3=0;
    for (int i = threadIdx.x; i < 4096; i += 256){
      unsigned char b = p[i];
      if (b == 0x3F && (i & 3) == 1) c0++;
      if (b == 0x3F && (i & 3) == 3) c1++;
      if (b == 1    && (i & 3) != 0) c2++;
      if (b == 1)                    c3++;
    }
    atomicAdd(&cnt[0], c0); atomicAdd(&cnt[1], c1);
    atomicAdd(&cnt[2], c2); atomicAdd(&cnt[3], c3);
    __syncthreads();
    if (threadIdx.x == 0){
      int mm;
      if      (cnt[0] > 0) mm = 0;
      else if (cnt[1] > 0) mm = 1;
      else if (cnt[2] > 0) mm = 3;
      else if (cnt[3] > 0) mm = 2;
      else                 mm = 0;
      flags[1] = mm;
    }
  } else {
    const u16* u = (const u16*)x;
    int c = 0;
    for (int i = threadIdx.x; i < 4096; i += 256){
      int ex = (u[i] >> 7) & 0xFF;
      if (ex >= 147) c++;
    }
    atomicAdd(&cnt[0], c);
    __syncthreads();
    if (threadIdx.x == 0) flags[0] = (cnt[0] > 32) ? 1 : 0;
  }
}

// -------- blocked repack for VALU paths (Wmu1, Wmu2, Wc1): [K][N] -> [kb][N][8] bf16 --------
struct WtP { const void* src[3]; u16* dst[3]; const int* flags; };

__global__ void wtrans_kernel(WtP a){
  const int Ks[3]  = {128, 100, 100};
  const int Ns[3]  = {100, 100,  50};
  const int KBs[3] = { 16,  13,  13};
  int m   = blockIdx.x >> 3;
  int sub = blockIdx.x & 7;
  int K = Ks[m], N = Ns[m], KB = KBs[m];
  const void* src = a.src[m];
  u16* dst = a.dst[m];
  int fmode = a.flags[0];
  int E = KB * N * 8;
  for (int e = sub*256 + threadIdx.x; e < E; e += 8*256){
    int idx = e >> 3, kc = e & 7;
    int n = idx % N, kb = idx / N;
    int k = kb*8 + kc;
    float v = (k < K) ? loadf(src, (size_t)k * N + n, fmode) : 0.f;
    dst[e] = f2bf(v);
  }
}

// -------- MFMA B-fragment repack: frag[nt][kc][lane][8] with B[k][n], n=lane&15, k=kc*32+(lane>>4)*8+j --------
struct FrP { const void* src[4]; u16* dst[4]; const int* flags; };

__global__ void fragk(FrP a){
  const int Ks[4]  = {128, 100, 100, 100};
  const int Ns[4]  = {300, 300, 100,  64};
  const int NTs[4] = { 20,  20,   8,   4};
  int m   = blockIdx.x >> 3;
  int sub = blockIdx.x & 7;
  int K = Ks[m], N = Ns[m];
  const void* src = a.src[m];
  u16* dst = a.dst[m];
  int fmode = a.flags[0];
  int E = NTs[m] * 2048;
  for (int e = sub*256 + threadIdx.x; e < E; e += 8*256){
    int j    = e & 7;
    int lane = (e >> 3) & 63;
    int kc   = (e >> 9) & 3;
    int nt   = e >> 11;
    int k = kc*32 + ((lane >> 4) << 3) + j;
    int n = nt*16 + (lane & 15);
    float v = (k < K && n < N) ? loadf(src, (size_t)k * N + n, fmode) : 0.f;
    dst[e] = f2bf(v);
  }
}

// ---------------- main persistent kernel ----------------
struct MainP {
  const void *x, *y, *mask;
  const void *bmu1, *bmu2, *bih, *bhh, *bl1, *bl2, *bc1, *bc2, *wc2;
  const u16 *Wmu1b, *Wmu2b, *Wc1b;
  const u16 *fih, *fhh, *fl1, *fl2;
  const int* flags;
  void* out;
};

__device__ __forceinline__ void load_win8(const void* Y, const void* M, int row0, int t,
                                          int fmode, int mmode, uint4* yv, u32& mb){
  mb = 0u;
  #pragma unroll
  for (int p = 0; p < 2; ++p){
    int idx = threadIdx.x + (p << 8);
    int r = idx >> 6, d = idx & 63;
    size_t base = ((size_t)(row0 + r)*64 + d)*200 + t;
    uint4 yw;
    if (fmode == 0){
      yw = *(const uint4*)((const u16*)Y + base);
    } else {
      const float* yf = (const float*)Y + base;
      float4 f0 = *(const float4*)yf;
      float4 f1 = *(const float4*)(yf + 4);
      yw.x = (u32)f2bf(f0.x) | ((u32)f2bf(f0.y) << 16);
      yw.y = (u32)f2bf(f0.z) | ((u32)f2bf(f0.w) << 16);
      yw.z = (u32)f2bf(f1.x) | ((u32)f2bf(f1.y) << 16);
      yw.w = (u32)f2bf(f1.z) | ((u32)f2bf(f1.w) << 16);
    }
    yv[p] = yw;
    u32 bits = 0;
    if (mmode == 0){
      uint4 mw = *(const uint4*)((const u16*)M + base);
      u32 w0 = mw.x, w1 = mw.y, w2 = mw.z, w3 = mw.w;
      if (w0 & 0xFFFFu) bits |= 1u;  if (w0 >> 16) bits |= 2u;
      if (w1 & 0xFFFFu) bits |= 4u;  if (w1 >> 16) bits |= 8u;
      if (w2 & 0xFFFFu) bits |= 16u; if (w2 >> 16) bits |= 32u;
      if (w3 & 0xFFFFu) bits |= 64u; if (w3 >> 16) bits |= 128u;
    } else if (mmode == 1){
      const float* mf = (const float*)M + base;
      float4 f0 = *(const float4*)mf;
      float4 f1 = *(const float4*)(mf + 4);
      if (f0.x != 0.f) bits |= 1u;  if (f0.y != 0.f) bits |= 2u;
      if (f0.z != 0.f) bits |= 4u;  if (f0.w != 0.f) bits |= 8u;
      if (f1.x != 0.f) bits |= 16u; if (f1.y != 0.f) bits |= 32u;
      if (f1.z != 0.f) bits |= 64u; if (f1.w != 0.f) bits |= 128u;
    } else if (mmode == 2){
      const int* mi = (const int*)M + base;
      int4 v0 = *(const int4*)mi;
      int4 v1 = *(const int4*)(mi + 4);
      if (v0.x) bits |= 1u;  if (v0.y) bits |= 2u;
      if (v0.z) bits |= 4u;  if (v0.w) bits |= 8u;
      if (v1.x) bits |= 16u; if (v1.y) bits |= 32u;
      if (v1.z) bits |= 64u; if (v1.w) bits |= 128u;
    } else {
      uint2 u = *(const uint2*)((const unsigned char*)M + base);
      #pragma unroll
      for (int q = 0; q < 4; ++q){
        if ((u.x >> (q*8)) & 0xFFu) bits |= 1u << q;
        if ((u.y >> (q*8)) & 0xFFu) bits |= 1u << (4 + q);
      }
    }
    mb |= bits << (p << 3);
  }
}

__global__ __launch_bounds__(256, 2) void gru_main(MainP P){
  // A-operand arrays: 16 rows (MFMA M=16); rows 8..15 zero forever.
  __shared__ u16   XIL[16*136];      // x_il bf16, row stride 136
  __shared__ u16   HB [16*136];      // h bf16 (A operand)
  __shared__ u16   HN2[16*136];      // tanh(h@Wl1+bl1) bf16 (A operand)
  // VALU-only arrays: 8 real rows (stores guarded ln<32).
  __shared__ float HF [RPB*108];     // final h fp32 (classifier only)
  __shared__ float SRZ[RPB*204];     // r|z preacts (also fp32 x staging in prologue)
  __shared__ float GXN[RPB*108];
  __shared__ float GHN[RPB*108];
  __shared__ u16   OS [RPB*64*16];   // out window: [r][d][slot], slot XOR-swizzled
  __shared__ float BIH[304], BHH[304], BL1[128], BL2[64], BC1[64], WC2[64], BMU1[112], BMU2[112];

  const int tid  = threadIdx.x;
  const int row0 = blockIdx.x * RPB;
  const int fmode = P.flags[0];
  const int mmode = P.flags[1];
  const int w  = tid >> 6;
  const int ln = tid & 63;
  const int col = ln & 15;
  const int q4  = (ln >> 4) << 2;

  // y/mask windows (8 steps)
  uint4 yc[2], yn[2];
  u32 mc, mn;
  load_win8(P.y, P.mask, row0, 0, fmode, mmode, yc, mc);
  load_win8(P.y, P.mask, row0, 8, fmode, mmode, yn, mn);

  // weight fragments -> registers (held across the whole t-loop)
  uint4 wih[5][4], whh[5][4], wl1[2][4], wl2[4];
  #pragma unroll
  for (int i = 0; i < 5; ++i){
    int nt = w + 4*i;
    #pragma unroll
    for (int kc = 0; kc < 4; ++kc){
      wih[i][kc] = *(const uint4*)(P.fih + (((nt*4 + kc) << 6) + ln)*8);
      whh[i][kc] = *(const uint4*)(P.fhh + (((nt*4 + kc) << 6) + ln)*8);
    }
  }
  #pragma unroll
  for (int i = 0; i < 2; ++i){
    int nt = w + 4*i;
    #pragma unroll
    for (int kc = 0; kc < 4; ++kc)
      wl1[i][kc] = *(const uint4*)(P.fl1 + (((nt*4 + kc) << 6) + ln)*8);
  }
  #pragma unroll
  for (int kc = 0; kc < 4; ++kc)
    wl2[kc] = *(const uint4*)(P.fl2 + (((w*4 + kc) << 6) + ln)*8);

  // zero LDS (A-operand pads incl. rows 8..15, classifier pads, out window)
  for (int i = tid; i < 16*136/2; i += 256){
    ((u32*)XIL)[i] = 0u; ((u32*)HB)[i] = 0u; ((u32*)HN2)[i] = 0u;
  }
  for (int i = tid; i < RPB*108; i += 256){ HF[i] = 0.f; GXN[i] = 0.f; GHN[i] = 0.f; }
  for (int i = tid; i < RPB*64*8; i += 256){ ((u32*)OS)[i] = 0u; }

  // biases
  for (int i = tid; i < 304; i += 256){
    BIH[i] = (i < 300) ? loadf(P.bih, i, fmode) : 0.f;
    BHH[i] = (i < 300) ? loadf(P.bhh, i, fmode) : 0.f;
  }
  if (tid < 128) BL1[tid] = (tid < 100) ? loadf(P.bl1, tid, fmode) : 0.f;
  if (tid < 64){
    BL2[tid] = loadf(P.bl2, tid, fmode);
    BC1[tid] = (tid < 50) ? loadf(P.bc1, tid, fmode) : 0.f;
    WC2[tid] = (tid < 50) ? loadf(P.wc2, tid, fmode) : 0.f;
  }
  if (tid < 112){
    BMU1[tid] = (tid < 100) ? loadf(P.bmu1, tid, fmode) : 0.f;
    BMU2[tid] = (tid < 100) ? loadf(P.bmu2, tid, fmode) : 0.f;
  }
  __syncthreads();

  // ---- prologue h0 = tanh(x@Wmu1+bmu1)@Wmu2+bmu2 (VALU, once) ----
  {
    int idx = tid;                         // RPB*32 == 256: single pass
    int r = idx >> 5, kq = idx & 31;
    size_t base = ((size_t)(row0 + r) << 7) + ((size_t)kq << 2);
    float v0, v1, v2, v3;
    if (fmode == 0){
      uint2 u = *(const uint2*)((const u16*)P.x + base);
      v0 = bf_lo(u.x); v1 = bf_hi(u.x); v2 = bf_lo(u.y); v3 = bf_hi(u.y);
    } else {
      float4 f = *(const float4*)((const float*)P.x + base);
      v0 = f.x; v1 = f.y; v2 = f.z; v3 = f.w;
    }
    float* dst = &SRZ[r*204 + (kq << 2)];
    dst[0] = v0; dst[1] = v1; dst[2] = v2; dst[3] = v3;
  }
  __syncthreads();
  #pragma unroll
  for (int p = 0; p < 4; ++p){
    int idx = tid + (p << 8);
    if (idx < RPB*100){
      int r = idx / 100, j = idx - r*100;
      GXN[r*108 + j] = ftanh(BMU1[j] + dotblk(&SRZ[r*204], P.Wmu1b, j, 100, 16));
    }
  }
  __syncthreads();
  float hreg[4];                            // h state in registers (map: idx=tid+256p -> (r,j))
  #pragma unroll
  for (int p = 0; p < 4; ++p){
    int idx = tid + (p << 8);
    if (idx < RPB*100){
      int r = idx / 100, j = idx - r*100;
      float hv = BMU2[j] + dotblk(&GXN[r*108], P.Wmu2b, j, 100, 13);
      hreg[p] = hv;
      HB[r*136 + j] = f2bf(hv);
    }
  }
  __syncthreads();

  // ---- t-loop ----
  for (int t = 0; t < TT; ++t){
    const int tc8 = t & 7;

    if (tc8 == 0 && t){
      #pragma unroll
      for (int p = 0; p < 2; ++p) yc[p] = yn[p];
      mc = mn;
      if (t + 8 < TT) load_win8(P.y, P.mask, row0, t + 8, fmode, mmode, yn, mn);
    }
    if ((t & 15) == 0 && t){
      // flush out window t-16..t-1 (un-swizzle words; full 32B per (r,d))
      int t0 = t - 16;
      const u32* ow = (const u32*)OS;
      #pragma unroll
      for (int p = 0; p < 2; ++p){
        int idx = tid + (p << 8);
        int r = idx >> 6, d = idx & 63;
        int swz = ((d >> 2) ^ r) & 7;
        int wb = idx << 3;
        u32 w0 = ow[wb + (0 ^ swz)], w1 = ow[wb + (1 ^ swz)];
        u32 w2 = ow[wb + (2 ^ swz)], w3 = ow[wb + (3 ^ swz)];
        u32 w4 = ow[wb + (4 ^ swz)], w5 = ow[wb + (5 ^ swz)];
        u32 w6 = ow[wb + (6 ^ swz)], w7 = ow[wb + (7 ^ swz)];
        size_t base = ((size_t)(row0 + r)*64 + d)*200 + t0;
        if (fmode == 0){
          u16* ob = (u16*)P.out + base;
          uint4 a; a.x = w0; a.y = w1; a.z = w2; a.w = w3;
          uint4 b; b.x = w4; b.y = w5; b.z = w6; b.w = w7;
          *(uint4*)ob = a;
          *(uint4*)(ob + 8) = b;
        } else {
          float* of = (float*)P.out + base;
          float4 f0 = {bf_lo(w0), bf_hi(w0), bf_lo(w1), bf_hi(w1)};
          float4 f1 = {bf_lo(w2), bf_hi(w2), bf_lo(w3), bf_hi(w3)};
          float4 f2 = {bf_lo(w4), bf_hi(w4), bf_lo(w5), bf_hi(w5)};
          float4 f3 = {bf_lo(w6), bf_hi(w6), bf_lo(w7), bf_hi(w7)};
          *(float4*)of = f0; *(float4*)(of+4) = f1;
          *(float4*)(of+8) = f2; *(float4*)(of+12) = f3;
        }
      }
    }

    // stage1: build x_il (teacher forcing; y_prev from bf16 out window)
    #pragma unroll
    for (int p = 0; p < 2; ++p){
      int idx = tid + (p << 8);
      int r = idx >> 6, d = idx & 63;
      u32 w01 = (tc8 & 2) ? yc[p].y : yc[p].x;
      u32 w23 = (tc8 & 2) ? yc[p].w : yc[p].z;
      u32 word = (tc8 & 4) ? w23 : w01;
      u16 yv16 = (tc8 & 1) ? (u16)(word >> 16) : (u16)(word & 0xFFFFu);
      bool mv = (mc >> ((p << 3) | tc8)) & 1u;
      int sl = ((t + 15) & 15) ^ ((((d >> 2) ^ r) & 7) << 1);
      u16 yp16 = OS[(idx << 4) + sl];
      u32 val = (u32)(mv ? yv16 : yp16) | ((mv ? 0x3F80u : 0u) << 16);
      *(u32*)(&XIL[r*136 + (d << 1)]) = val;
    }
    __syncthreads();

    // stage2: gx = x_il@Wih, gh = h@Whh (MFMA; C rows 8..15 discarded)
    {
      uint4 xa[4], ha[4];
      #pragma unroll
      for (int kc = 0; kc < 4; ++kc){
        int ao = (ln & 15)*136 + kc*32 + ((ln >> 4) << 3);
        xa[kc] = *(const uint4*)(&XIL[ao]);
        ha[kc] = *(const uint4*)(&HB[ao]);
      }
      #pragma unroll
      for (int i = 0; i < 3; ++i){          // nt <= 11: all cols < 200, shared acc
        f32x4 ac = {0.f, 0.f, 0.f, 0.f};
        #pragma unroll
        for (int kc = 0; kc < 4; ++kc) ac = mfma16(xa[kc], wih[i][kc], ac);
        #pragma unroll
        for (int kc = 0; kc < 4; ++kc) ac = mfma16(ha[kc], whh[i][kc], ac);
        if (ln < 32){                       // rows q4+reg in 0..7 only
          int n = (w + 4*i)*16 + col;
          float bb = BIH[n] + BHH[n];
          #pragma unroll
          for (int reg = 0; reg < 4; ++reg)
            SRZ[(q4 + reg)*204 + n] = ac[reg] + bb;
        }
      }
      #pragma unroll
      for (int i = 3; i < 5; ++i){          // nt 12..19: may split r/z vs n-gate
        f32x4 ax = {0.f,0.f,0.f,0.f}, ah = {0.f,0.f,0.f,0.f};
        #pragma unroll
        for (int kc = 0; kc < 4; ++kc){
          ax = mfma16(xa[kc], wih[i][kc], ax);
          ah = mfma16(ha[kc], whh[i][kc], ah);
        }
        if (ln < 32){
          int n = (w + 4*i)*16 + col;
          if (n < 200){
            float bb = BIH[n] + BHH[n];
            #pragma unroll
            for (int reg = 0; reg < 4; ++reg)
              SRZ[(q4 + reg)*204 + n] = ax[reg] + ah[reg] + bb;
          } else if (n < 304){
            float b1 = BIH[n], b2 = BHH[n];
            #pragma unroll
            for (int reg = 0; reg < 4; ++reg){
              GXN[(q4 + reg)*108 + n - 200] = ax[reg] + b1;
              GHN[(q4 + reg)*108 + n - 200] = ah[reg] + b2;
            }
          }
        }
      }
    }
    __syncthreads();

    // stage3: gates + h update (h in registers)
    #pragma unroll
    for (int p = 0; p < 4; ++p){
      int idx = tid + (p << 8);
      if (idx < RPB*100){
        int r = idx / 100, j = idx - r*100;
        float rr = fsig(SRZ[r*204 + j]);
        float zz = fsig(SRZ[r*204 + 100 + j]);
        float nn = ftanh(GXN[r*108 + j] + rr*GHN[r*108 + j]);
        float hv = (1.f - zz)*nn + zz*hreg[p];
        hreg[p] = hv;
        HB[r*136 + j] = f2bf(hv);
      }
    }
    __syncthreads();

    // stage4: hn2 = tanh(h@Wl1+bl1) (MFMA)
    {
      uint4 ha[4];
      #pragma unroll
      for (int kc = 0; kc < 4; ++kc){
        int ao = (ln & 15)*136 + kc*32 + ((ln >> 4) << 3);
        ha[kc] = *(const uint4*)(&HB[ao]);
      }
      #pragma unroll
      for (int i = 0; i < 2; ++i){
        f32x4 ac = {0.f,0.f,0.f,0.f};
        #pragma unroll
        for (int kc = 0; kc < 4; ++kc) ac = mfma16(ha[kc], wl1[i][kc], ac);
        if (ln < 32){
          int n = (w + 4*i)*16 + col;
          #pragma unroll
          for (int reg = 0; reg < 4; ++reg)
            HN2[(q4 + reg)*136 + n] = f2bf(ftanh(ac[reg] + BL1[n]));
        }
      }
    }
    __syncthreads();

    // stage5: out_t = hn2@Wl2+bl2 (MFMA) -> out window (swizzled slot)
    {
      uint4 na[4];
      #pragma unroll
      for (int kc = 0; kc < 4; ++kc){
        int ao = (ln & 15)*136 + kc*32 + ((ln >> 4) << 3);
        na[kc] = *(const uint4*)(&HN2[ao]);
      }
      f32x4 ac = {0.f,0.f,0.f,0.f};
      #pragma unroll
      for (int kc = 0; kc < 4; ++kc) ac = mfma16(na[kc], wl2[kc], ac);
      if (ln < 32){
        int d = w*16 + col;
        #pragma unroll
        for (int reg = 0; reg < 4; ++reg){
          float o = ac[reg] + BL2[d];
          int rr = q4 + reg;
          int sl = (t & 15) ^ ((((d >> 2) ^ rr) & 7) << 1);
          OS[((rr*64 + d) << 4) + sl] = f2bf(o);
        }
      }
    }
    __syncthreads();
  }

  // final flush: t = 192..199 (words 0..3 of each line, un-swizzled)
  {
    int t0 = TT - 8;
    const u32* ow = (const u32*)OS;
    #pragma unroll
    for (int p = 0; p < 2; ++p){
      int idx = tid + (p << 8);
      int r = idx >> 6, d = idx & 63;
      int swz = ((d >> 2) ^ r) & 7;
      int wb = idx << 3;
      u32 w0 = ow[wb + (0 ^ swz)], w1 = ow[wb + (1 ^ swz)];
      u32 w2 = ow[wb + (2 ^ swz)], w3 = ow[wb + (3 ^ swz)];
      size_t base = ((size_t)(row0 + r)*64 + d)*200 + t0;
      if (fmode == 0){
        uint4 a; a.x = w0; a.y = w1; a.z = w2; a.w = w3;
        *(uint4*)((u16*)P.out + base) = a;
      } else {
        float* of = (float*)P.out + base;
        float4 f0 = {bf_lo(w0), bf_hi(w0), bf_lo(w1), bf_hi(w1)};
        float4 f1 = {bf_lo(w2), bf_hi(w2), bf_lo(w3), bf_hi(w3)};
        *(float4*)of = f0; *(float4*)(of+4) = f1;
      }
    }
  }

  // spill h registers to LDS for the classifier
  #pragma unroll
  for (int p = 0; p < 4; ++p){
    int idx = tid + (p << 8);
    if (idx < RPB*100){
      int r = idx / 100, j = idx - r*100;
      HF[r*108 + j] = hreg[p];
    }
  }
  __syncthreads();

  // classifier: sigmoid(relu(h@Wc1+bc1)@Wc2+bc2)
  #pragma unroll
  for (int p = 0; p < 2; ++p){
    int idx = tid + (p << 8);
    if (idx < RPB*50){
      int r = idx / 50, j = idx - r*50;
      float c = BC1[j] + dotblk(&HF[r*108], P.Wc1b, j, 50, 13);
      GXN[r*108 + j] = fmaxf(c, 0.f);
    }
  }
  __syncthreads();
  if (tid < RPB){
    float oc = loadf(P.bc2, 0, fmode);
    for (int j = 0; j < 50; ++j) oc += GXN[tid*108 + j]*WC2[j];
    float sg = fsig(oc);
    size_t off = (size_t)BSZ*YD*TT + row0 + tid;
    if (fmode == 0) ((u16*)P.out)[off] = f2bf(sg);
    else            ((float*)P.out)[off] = sg;
  }
}

extern "C" void kernel_launch(void* const* d_in, const int* in_sizes, int n_in,
                              void* d_out, int out_size, void* d_ws, size_t ws_size,
                              hipStream_t stream){
  // ws: [0..256) flags; then u16 region:
  //   Wmu1b 12800 | Wmu2b 10400 | Wc1b 5200 | fih 40960 | fhh 40960 | fl1 16384 | fl2 8192
  int* flags = (int*)d_ws;
  u16* wb = (u16*)((char*)d_ws + 256);
  u16* Wmu1b = wb;
  u16* Wmu2b = wb + 12800;
  u16* Wc1b  = wb + 23200;
  u16* fih   = wb + 28400;
  u16* fhh   = wb + 69360;
  u16* fl1   = wb + 110320;
  u16* fl2   = wb + 126704;

  detect_kernel<<<2, 256, 0, stream>>>(d_in[2], d_in[0], flags);

  WtP wp;
  wp.flags = flags;
  wp.src[0] = d_in[3];  wp.dst[0] = Wmu1b;
  wp.src[1] = d_in[5];  wp.dst[1] = Wmu2b;
  wp.src[2] = d_in[19]; wp.dst[2] = Wc1b;
  wtrans_kernel<<<24, 256, 0, stream>>>(wp);

  FrP fp;
  fp.flags = flags;
  fp.src[0] = d_in[11]; fp.dst[0] = fih;
  fp.src[1] = d_in[13]; fp.dst[1] = fhh;
  fp.src[2] = d_in[15]; fp.dst[2] = fl1;
  fp.src[3] = d_in[17]; fp.dst[3] = fl2;
  fragk<<<32, 256, 0, stream>>>(fp);

  MainP mp;
  mp.x = d_in[0]; mp.y = d_in[1]; mp.mask = d_in[2];
  mp.bmu1 = d_in[4];  mp.bmu2 = d_in[6];
  mp.bih  = d_in[12]; mp.bhh  = d_in[14];
  mp.bl1  = d_in[16]; mp.bl2  = d_in[18];
  mp.bc1  = d_in[20]; mp.bc2  = d_in[22]; mp.wc2 = d_in[21];
  mp.Wmu1b = Wmu1b; mp.Wmu2b = Wmu2b; mp.Wc1b = Wc1b;
  mp.fih = fih; mp.fhh = fhh; mp.fl1 = fl1; mp.fl2 = fl2;
  mp.flags = flags; mp.out = d_out;
  gru_main<<<NBLK, 256, 0, stream>>>(mp);
}

// Round 2
// 2407.520 us; speedup vs baseline: 1.1744x; 1.1744x over previous
//
#include <hip/hip_runtime.h>
#include <hip/hip_bf16.h>

// GRU_teach round 3: 8 waves/block on the round-1 memory regime.
// - RPB=16, 256 blocks (EXACT round-1 global access pattern: 820 MB fetch,
//   proven L2-friendly). 512 threads/block => 8 waves/CU (2/SIMD) for
//   latency overlap, halved per-wave serial work per step.
// - Round-2 regression root cause: RPB=8/512 blocks thrashed per-XCD L2
//   (t-strided y/mask/out lines must survive ~32 steps; working set >4MiB)
//   -> 6.4 GB L2-fill traffic. Reverted that; kept the memory-neutral wins:
//   OS slot XOR-swizzle (16-way bank conflict fix) + h state in registers.
// - MFMA tiles full 16 rows again (no half-empty C tiles).

#define BSZ   4096
#define XD    128
#define YD    64
#define TT    200
#define NH3   300
#define RPB   16
#define NBLK  (BSZ / RPB)
#define NTHR  512

typedef unsigned short u16;
typedef unsigned int   u32;
typedef __attribute__((ext_vector_type(8))) short s16x8;
typedef __attribute__((ext_vector_type(4))) float f32x4;

__device__ __forceinline__ float bf_lo(u32 u){ return __uint_as_float(u << 16); }
__device__ __forceinline__ float bf_hi(u32 u){ return __uint_as_float(u & 0xFFFF0000u); }
__device__ __forceinline__ u16 f2bf(float f){
  u32 u = __float_as_uint(f);
  u32 r = (u + 0x7FFFu + ((u >> 16) & 1u)) >> 16;   // RNE
  return (u16)r;
}
__device__ __forceinline__ float loadf(const void* p, size_t i, int fmode){
  return (fmode == 0) ? __uint_as_float(((u32)((const u16*)p)[i]) << 16)
                      : ((const float*)p)[i];
}
__device__ __forceinline__ float fsig(float x){ return 1.f/(1.f + __expf(-x)); }
__device__ __forceinline__ float ftanh(float x){ float e = __expf(2.f*x); return 1.f - 2.f/(e + 1.f); }

__device__ __forceinline__ f32x4 mfma16(uint4 a, uint4 b, f32x4 c){
  s16x8 as, bs;
  __builtin_memcpy(&as, &a, 16);
  __builtin_memcpy(&bs, &b, 16);
  return __builtin_amdgcn_mfma_f32_16x16x32_bf16(as, bs, c, 0, 0, 0);
}

// dot of fp32 LDS row (KB*8 floats, zero-padded) with k-blocked bf16 weights, column n of N
__device__ __forceinline__ float dotblk(const float* xr, const u16* wb, int n, int N, int KB){
  float a = 0.f;
  const uint4* wp = (const uint4*)wb;
  #pragma unroll
  for (int kb = 0; kb < KB; ++kb){
    uint4 u = wp[kb * N + n];
    const float4* xp = (const float4*)(xr + (kb << 3));
    float4 x0 = xp[0], x1 = xp[1];
    a += x0.x*bf_lo(u.x) + x0.y*bf_hi(u.x) + x0.z*bf_lo(u.y) + x0.w*bf_hi(u.y);
    a += x1.x*bf_lo(u.z) + x1.y*bf_hi(u.z) + x1.z*bf_lo(u.w) + x1.w*bf_hi(u.w);
  }
  return a;
}

// ---------------- dtype detection (unchanged, verified) ----------------
__global__ void detect_kernel(const void* mask, const void* x, int* flags){
  __shared__ int cnt[4];
  if (threadIdx.x < 4) cnt[threadIdx.x] = 0;
  __syncthreads();
  if (blockIdx.x == 0){
    const unsigned char* p = (const unsigned char*)mask;
    int c0=0, c1=0, c2=0, c3=0;
    for (int i = threadIdx.x; i < 4096; i += 256){
      unsigned char b = p[i];
      if (b == 0x3F && (i & 3) == 1) c0++;
      if (b == 0x3F && (i & 3) == 3) c1++;
      if (b == 1    && (i & 3) != 0) c2++;
      if (b == 1)                    c3++;
    }
    atomicAdd(&cnt[0], c0); atomicAdd(&cnt[1], c1);
    atomicAdd(&cnt[2], c2); atomicAdd(&cnt[3], c3);
    __syncthreads();
    if (threadIdx.x == 0){
      int mm;
      if      (cnt[0] > 0) mm = 0;
      else if (cnt[1] > 0) mm = 1;
      else if (cnt[2] > 0) mm = 3;
      else if (cnt[3] > 0) mm = 2;
      else                 mm = 0;
      flags[1] = mm;
    }
  } else {
    const u16* u = (const u16*)x;
    int c = 0;
    for (int i = threadIdx.x; i < 4096; i += 256){
      int ex = (u[i] >> 7) & 0xFF;
      if (ex >= 147) c++;
    }
    atomicAdd(&cnt[0], c);
    __syncthreads();
    if (threadIdx.x == 0) flags[0] = (cnt[0] > 32) ? 1 : 0;
  }
}

// -------- blocked repack for VALU paths (Wmu1, Wmu2, Wc1): [K][N] -> [kb][N][8] bf16 --------
struct WtP { const void* src[3]; u16* dst[3]; const int* flags; };

__global__ void wtrans_kernel(WtP a){
  const int Ks[3]  = {128, 100, 100};
  const int Ns[3]  = {100, 100,  50};
  const int KBs[3] = { 16,  13,  13};
  int m   = blockIdx.x >> 3;
  int sub = blockIdx.x & 7;
  int K = Ks[m], N = Ns[m], KB = KBs[m];
  const void* src = a.src[m];
  u16* dst = a.dst[m];
  int fmode = a.flags[0];
  int E = KB * N * 8;
  for (int e = sub*256 + threadIdx.x; e < E; e += 8*256){
    int idx = e >> 3, kc = e & 7;
    int n = idx % N, kb = idx / N;
    int k = kb*8 + kc;
    float v = (k < K) ? loadf(src, (size_t)k * N + n, fmode) : 0.f;
    dst[e] = f2bf(v);
  }
}

// -------- MFMA B-fragment repack: frag[nt][kc][lane][8] with B[k][n], n=lane&15, k=kc*32+(lane>>4)*8+j --------
struct FrP { const void* src[4]; u16* dst[4]; const int* flags; };

__global__ void fragk(FrP a){
  const int Ks[4]  = {128, 100, 100, 100};
  const int Ns[4]  = {300, 300, 100,  64};
  const int NTs[4] = { 20,  20,   8,   4};
  int m   = blockIdx.x >> 3;
  int sub = blockIdx.x & 7;
  int K = Ks[m], N = Ns[m];
  const void* src = a.src[m];
  u16* dst = a.dst[m];
  int fmode = a.flags[0];
  int E = NTs[m] * 2048;
  for (int e = sub*256 + threadIdx.x; e < E; e += 8*256){
    int j    = e & 7;
    int lane = (e >> 3) & 63;
    int kc   = (e >> 9) & 3;
    int nt   = e >> 11;
    int k = kc*32 + ((lane >> 4) << 3) + j;
    int n = nt*16 + (lane & 15);
    float v = (k < K && n < N) ? loadf(src, (size_t)k * N + n, fmode) : 0.f;
    dst[e] = f2bf(v);
  }
}

// ---------------- main persistent kernel ----------------
struct MainP {
  const void *x, *y, *mask;
  const void *bmu1, *bmu2, *bih, *bhh, *bl1, *bl2, *bc1, *bc2, *wc2;
  const u16 *Wmu1b, *Wmu2b, *Wc1b;
  const u16 *fih, *fhh, *fl1, *fl2;
  const int* flags;
  void* out;
};

// 1024 (r,d) pairs over 512 threads: 2 pairs/thread.
__device__ __forceinline__ void load_win8(const void* Y, const void* M, int row0, int t,
                                          int fmode, int mmode, uint4* yv, u32& mb){
  mb = 0u;
  #pragma unroll
  for (int p = 0; p < 2; ++p){
    int idx = threadIdx.x + (p << 9);
    int r = idx >> 6, d = idx & 63;
    size_t base = ((size_t)(row0 + r)*64 + d)*200 + t;
    uint4 yw;
    if (fmode == 0){
      yw = *(const uint4*)((const u16*)Y + base);
    } else {
      const float* yf = (const float*)Y + base;
      float4 f0 = *(const float4*)yf;
      float4 f1 = *(const float4*)(yf + 4);
      yw.x = (u32)f2bf(f0.x) | ((u32)f2bf(f0.y) << 16);
      yw.y = (u32)f2bf(f0.z) | ((u32)f2bf(f0.w) << 16);
      yw.z = (u32)f2bf(f1.x) | ((u32)f2bf(f1.y) << 16);
      yw.w = (u32)f2bf(f1.z) | ((u32)f2bf(f1.w) << 16);
    }
    yv[p] = yw;
    u32 bits = 0;
    if (mmode == 0){
      uint4 mw = *(const uint4*)((const u16*)M + base);
      u32 w0 = mw.x, w1 = mw.y, w2 = mw.z, w3 = mw.w;
      if (w0 & 0xFFFFu) bits |= 1u;  if (w0 >> 16) bits |= 2u;
      if (w1 & 0xFFFFu) bits |= 4u;  if (w1 >> 16) bits |= 8u;
      if (w2 & 0xFFFFu) bits |= 16u; if (w2 >> 16) bits |= 32u;
      if (w3 & 0xFFFFu) bits |= 64u; if (w3 >> 16) bits |= 128u;
    } else if (mmode == 1){
      const float* mf = (const float*)M + base;
      float4 f0 = *(const float4*)mf;
      float4 f1 = *(const float4*)(mf + 4);
      if (f0.x != 0.f) bits |= 1u;  if (f0.y != 0.f) bits |= 2u;
      if (f0.z != 0.f) bits |= 4u;  if (f0.w != 0.f) bits |= 8u;
      if (f1.x != 0.f) bits |= 16u; if (f1.y != 0.f) bits |= 32u;
      if (f1.z != 0.f) bits |= 64u; if (f1.w != 0.f) bits |= 128u;
    } else if (mmode == 2){
      const int* mi = (const int*)M + base;
      int4 v0 = *(const int4*)mi;
      int4 v1 = *(const int4*)(mi + 4);
      if (v0.x) bits |= 1u;  if (v0.y) bits |= 2u;
      if (v0.z) bits |= 4u;  if (v0.w) bits |= 8u;
      if (v1.x) bits |= 16u; if (v1.y) bits |= 32u;
      if (v1.z) bits |= 64u; if (v1.w) bits |= 128u;
    } else {
      uint2 u = *(const uint2*)((const unsigned char*)M + base);
      #pragma unroll
      for (int q = 0; q < 4; ++q){
        if ((u.x >> (q*8)) & 0xFFu) bits |= 1u << q;
        if ((u.y >> (q*8)) & 0xFFu) bits |= 1u << (4 + q);
      }
    }
    mb |= bits << (p << 3);
  }
}

__global__ __launch_bounds__(NTHR, 2) void gru_main(MainP P){
  __shared__ u16   XIL[RPB*136];     // x_il bf16, row stride 136
  __shared__ u16   HB [RPB*136];     // h bf16 (A operand)
  __shared__ u16   HN2[RPB*136];     // tanh(h@Wl1+bl1) bf16
  __shared__ float HF [RPB*108];     // final h fp32 (classifier only)
  __shared__ float SRZ[RPB*204];     // r|z preacts (also fp32 x staging in prologue)
  __shared__ float GXN[RPB*108];
  __shared__ float GHN[RPB*108];
  __shared__ u16   OS [RPB*64*16];   // out window: [r][d][slot], slot XOR-swizzled
  __shared__ float BIH[304], BHH[304], BL1[128], BL2[64], BC1[64], WC2[64], BMU1[112], BMU2[112];

  const int tid  = threadIdx.x;
  const int row0 = blockIdx.x * RPB;
  const int fmode = P.flags[0];
  const int mmode = P.flags[1];
  const int w  = tid >> 6;           // wave 0..7
  const int ln = tid & 63;
  const int col = ln & 15;
  const int q4  = (ln >> 4) << 2;

  // y/mask windows (8 steps), 2 pairs/thread
  uint4 yc[2], yn[2];
  u32 mc, mn;
  load_win8(P.y, P.mask, row0, 0, fmode, mmode, yc, mc);
  load_win8(P.y, P.mask, row0, 8, fmode, mmode, yn, mn);

  // weight fragments -> registers. 20 ih/hh tiles over 8 waves: nt = w + 8*i.
  uint4 wih[3][4], whh[3][4], wl1[4], wl2[4];
  #pragma unroll
  for (int i = 0; i < 3; ++i){
    int nt = w + 8*i;
    #pragma unroll
    for (int kc = 0; kc < 4; ++kc){
      uint4 zi = {0u,0u,0u,0u};
      wih[i][kc] = zi; whh[i][kc] = zi;
      if (nt < 20){
        wih[i][kc] = *(const uint4*)(P.fih + (((nt*4 + kc) << 6) + ln)*8);
        whh[i][kc] = *(const uint4*)(P.fhh + (((nt*4 + kc) << 6) + ln)*8);
      }
    }
  }
  #pragma unroll
  for (int kc = 0; kc < 4; ++kc){    // 8 l1 tiles over 8 waves: nt = w
    wl1[kc] = *(const uint4*)(P.fl1 + (((w*4 + kc) << 6) + ln)*8);
  }
  #pragma unroll
  for (int kc = 0; kc < 4; ++kc){    // 4 l2 tiles: waves 0..3 only
    uint4 zi = {0u,0u,0u,0u};
    wl2[kc] = zi;
    if (w < 4) wl2[kc] = *(const uint4*)(P.fl2 + (((w*4 + kc) << 6) + ln)*8);
  }

  // zero LDS
  for (int i = tid; i < RPB*136/2; i += NTHR){
    ((u32*)XIL)[i] = 0u; ((u32*)HB)[i] = 0u; ((u32*)HN2)[i] = 0u;
  }
  for (int i = tid; i < RPB*108; i += NTHR){ HF[i] = 0.f; GXN[i] = 0.f; GHN[i] = 0.f; }
  for (int i = tid; i < RPB*64*8; i += NTHR){ ((u32*)OS)[i] = 0u; }

  // biases
  for (int i = tid; i < 304; i += NTHR){
    BIH[i] = (i < 300) ? loadf(P.bih, i, fmode) : 0.f;
    BHH[i] = (i < 300) ? loadf(P.bhh, i, fmode) : 0.f;
  }
  if (tid < 128) BL1[tid] = (tid < 100) ? loadf(P.bl1, tid, fmode) : 0.f;
  if (tid < 64){
    BL2[tid] = loadf(P.bl2, tid, fmode);
    BC1[tid] = (tid < 50) ? loadf(P.bc1, tid, fmode) : 0.f;
    WC2[tid] = (tid < 50) ? loadf(P.wc2, tid, fmode) : 0.f;
  }
  if (tid < 112){
    BMU1[tid] = (tid < 100) ? loadf(P.bmu1, tid, fmode) : 0.f;
    BMU2[tid] = (tid < 100) ? loadf(P.bmu2, tid, fmode) : 0.f;
  }
  __syncthreads();

  // ---- prologue h0 = tanh(x@Wmu1+bmu1)@Wmu2+bmu2 (VALU, once) ----
  {
    int idx = tid;                   // RPB*32 == 512: single pass
    int r = idx >> 5, kq = idx & 31;
    size_t base = ((size_t)(row0 + r) << 7) + ((size_t)kq << 2);
    float v0, v1, v2, v3;
    if (fmode == 0){
      uint2 u = *(const uint2*)((const u16*)P.x + base);
      v0 = bf_lo(u.x); v1 = bf_hi(u.x); v2 = bf_lo(u.y); v3 = bf_hi(u.y);
    } else {
      float4 f = *(const float4*)((const float*)P.x + base);
      v0 = f.x; v1 = f.y; v2 = f.z; v3 = f.w;
    }
    float* dst = &SRZ[r*204 + (kq << 2)];
    dst[0] = v0; dst[1] = v1; dst[2] = v2; dst[3] = v3;
  }
  __syncthreads();
  #pragma unroll
  for (int p = 0; p < 4; ++p){
    int idx = tid + (p << 9);
    if (idx < RPB*100){
      int r = idx / 100, j = idx - r*100;
      GXN[r*108 + j] = ftanh(BMU1[j] + dotblk(&SRZ[r*204], P.Wmu1b, j, 100, 16));
    }
  }
  __syncthreads();
  float hreg[4];                      // h state in registers (map: idx=tid+512p -> (r,j))
  #pragma unroll
  for (int p = 0; p < 4; ++p){
    hreg[p] = 0.f;
    int idx = tid + (p << 9);
    if (idx < RPB*100){
      int r = idx / 100, j = idx - r*100;
      float hv = BMU2[j] + dotblk(&GXN[r*108], P.Wmu2b, j, 100, 13);
      hreg[p] = hv;
      HB[r*136 + j] = f2bf(hv);
    }
  }
  __syncthreads();

  // ---- t-loop ----
  for (int t = 0; t < TT; ++t){
    const int tc8 = t & 7;

    if (tc8 == 0 && t){
      #pragma unroll
      for (int p = 0; p < 2; ++p) yc[p] = yn[p];
      mc = mn;
      if (t + 8 < TT) load_win8(P.y, P.mask, row0, t + 8, fmode, mmode, yn, mn);
    }
    if ((t & 15) == 0 && t){
      // flush out window t-16..t-1 (un-swizzle words; full 32B per (r,d))
      int t0 = t - 16;
      const u32* ow = (const u32*)OS;
      #pragma unroll
      for (int p = 0; p < 2; ++p){
        int idx = tid + (p << 9);
        int r = idx >> 6, d = idx & 63;
        int swz = ((d >> 2) ^ r) & 7;
        int wb = idx << 3;
        u32 w0 = ow[wb + (0 ^ swz)], w1 = ow[wb + (1 ^ swz)];
        u32 w2 = ow[wb + (2 ^ swz)], w3 = ow[wb + (3 ^ swz)];
        u32 w4 = ow[wb + (4 ^ swz)], w5 = ow[wb + (5 ^ swz)];
        u32 w6 = ow[wb + (6 ^ swz)], w7 = ow[wb + (7 ^ swz)];
        size_t base = ((size_t)(row0 + r)*64 + d)*200 + t0;
        if (fmode == 0){
          u16* ob = (u16*)P.out + base;
          uint4 a; a.x = w0; a.y = w1; a.z = w2; a.w = w3;
          uint4 b; b.x = w4; b.y = w5; b.z = w6; b.w = w7;
          *(uint4*)ob = a;
          *(uint4*)(ob + 8) = b;
        } else {
          float* of = (float*)P.out + base;
          float4 f0 = {bf_lo(w0), bf_hi(w0), bf_lo(w1), bf_hi(w1)};
          float4 f1 = {bf_lo(w2), bf_hi(w2), bf_lo(w3), bf_hi(w3)};
          float4 f2 = {bf_lo(w4), bf_hi(w4), bf_lo(w5), bf_hi(w5)};
          float4 f3 = {bf_lo(w6), bf_hi(w6), bf_lo(w7), bf_hi(w7)};
          *(float4*)of = f0; *(float4*)(of+4) = f1;
          *(float4*)(of+8) = f2; *(float4*)(of+12) = f3;
        }
      }
    }

    // stage1: build x_il (teacher forcing; y_prev from bf16 out window)
    #pragma unroll
    for (int p = 0; p < 2; ++p){
      int idx = tid + (p << 9);
      int r = idx >> 6, d = idx & 63;
      u32 w01 = (tc8 & 2) ? yc[p].y : yc[p].x;
      u32 w23 = (tc8 & 2) ? yc[p].w : yc[p].z;
      u32 word = (tc8 & 4) ? w23 : w01;
      u16 yv16 = (tc8 & 1) ? (u16)(word >> 16) : (u16)(word & 0xFFFFu);
      bool mv = (mc >> ((p << 3) | tc8)) & 1u;
      int sl = ((t + 15) & 15) ^ ((((d >> 2) ^ r) & 7) << 1);
      u16 yp16 = OS[(idx << 4) + sl];
      u32 val = (u32)(mv ? yv16 : yp16) | ((mv ? 0x3F80u : 0u) << 16);
      *(u32*)(&XIL[r*136 + (d << 1)]) = val;
    }
    __syncthreads();

    // stage2: gx = x_il@Wih, gh = h@Whh (MFMA, 20 tiles over 8 waves)
    {
      uint4 xa[4], ha[4];
      #pragma unroll
      for (int kc = 0; kc < 4; ++kc){
        int ao = (ln & 15)*136 + kc*32 + ((ln >> 4) << 3);
        xa[kc] = *(const uint4*)(&XIL[ao]);
        ha[kc] = *(const uint4*)(&HB[ao]);
      }
      #pragma unroll
      for (int i = 0; i < 3; ++i){
        int nt = w + 8*i;
        if (nt < 20){
          int n = nt*16 + col;
          if (nt < 12){                    // all cols < 200: shared acc
            f32x4 ac = {0.f, 0.f, 0.f, 0.f};
            #pragma unroll
            for (int kc = 0; kc < 4; ++kc) ac = mfma16(xa[kc], wih[i][kc], ac);
            #pragma unroll
            for (int kc = 0; kc < 4; ++kc) ac = mfma16(ha[kc], whh[i][kc], ac);
            float bb = BIH[n] + BHH[n];
            #pragma unroll
            for (int reg = 0; reg < 4; ++reg)
              SRZ[(q4 + reg)*204 + n] = ac[reg] + bb;
          } else {                         // may split r/z vs n-gate
            f32x4 ax = {0.f,0.f,0.f,0.f}, ah = {0.f,0.f,0.f,0.f};
            #pragma unroll
            for (int kc = 0; kc < 4; ++kc){
              ax = mfma16(xa[kc], wih[i][kc], ax);
              ah = mfma16(ha[kc], whh[i][kc], ah);
            }
            if (n < 200){
              float bb = BIH[n] + BHH[n];
              #pragma unroll
              for (int reg = 0; reg < 4; ++reg)
                SRZ[(q4 + reg)*204 + n] = ax[reg] + ah[reg] + bb;
            } else if (n < 304){
              float b1 = BIH[n], b2 = BHH[n];
              #pragma unroll
              for (int reg = 0; reg < 4; ++reg){
                GXN[(q4 + reg)*108 + n - 200] = ax[reg] + b1;
                GHN[(q4 + reg)*108 + n - 200] = ah[reg] + b2;
              }
            }
          }
        }
      }
    }
    __syncthreads();

    // stage3: gates + h update (h in registers)
    #pragma unroll
    for (int p = 0; p < 4; ++p){
      int idx = tid + (p << 9);
      if (idx < RPB*100){
        int r = idx / 100, j = idx - r*100;
        float rr = fsig(SRZ[r*204 + j]);
        float zz = fsig(SRZ[r*204 + 100 + j]);
        float nn = ftanh(GXN[r*108 + j] + rr*GHN[r*108 + j]);
        float hv = (1.f - zz)*nn + zz*hreg[p];
        hreg[p] = hv;
        HB[r*136 + j] = f2bf(hv);
      }
    }
    __syncthreads();

    // stage4: hn2 = tanh(h@Wl1+bl1) (MFMA, 8 tiles over 8 waves: nt = w)
    {
      uint4 ha[4];
      #pragma unroll
      for (int kc = 0; kc < 4; ++kc){
        int ao = (ln & 15)*136 + kc*32 + ((ln >> 4) << 3);
        ha[kc] = *(const uint4*)(&HB[ao]);
      }
      f32x4 ac = {0.f,0.f,0.f,0.f};
      #pragma unroll
      for (int kc = 0; kc < 4; ++kc) ac = mfma16(ha[kc], wl1[kc], ac);
      int n = w*16 + col;
      #pragma unroll
      for (int reg = 0; reg < 4; ++reg)
        HN2[(q4 + reg)*136 + n] = f2bf(ftanh(ac[reg] + BL1[n]));
    }
    __syncthreads();

    // stage5: out_t = hn2@Wl2+bl2 (MFMA, 4 tiles: waves 0..3) -> out window
    if (w < 4){
      uint4 na[4];
      #pragma unroll
      for (int kc = 0; kc < 4; ++kc){
        int ao = (ln & 15)*136 + kc*32 + ((ln >> 4) << 3);
        na[kc] = *(const uint4*)(&HN2[ao]);
      }
      f32x4 ac = {0.f,0.f,0.f,0.f};
      #pragma unroll
      for (int kc = 0; kc < 4; ++kc) ac = mfma16(na[kc], wl2[kc], ac);
      int d = w*16 + col;
      #pragma unroll
      for (int reg = 0; reg < 4; ++reg){
        float o = ac[reg] + BL2[d];
        int rr = q4 + reg;
        int sl = (t & 15) ^ ((((d >> 2) ^ rr) & 7) << 1);
        OS[((rr*64 + d) << 4) + sl] = f2bf(o);
      }
    }
    __syncthreads();
  }

  // final flush: t = 192..199 (logical words 0..3, un-swizzled)
  {
    int t0 = TT - 8;
    const u32* ow = (const u32*)OS;
    #pragma unroll
    for (int p = 0; p < 2; ++p){
      int idx = tid + (p << 9);
      int r = idx >> 6, d = idx & 63;
      int swz = ((d >> 2) ^ r) & 7;
      int wb = idx << 3;
      u32 w0 = ow[wb + (0 ^ swz)], w1 = ow[wb + (1 ^ swz)];
      u32 w2 = ow[wb + (2 ^ swz)], w3 = ow[wb + (3 ^ swz)];
      size_t base = ((size_t)(row0 + r)*64 + d)*200 + t0;
      if (fmode == 0){
        uint4 a; a.x = w0; a.y = w1; a.z = w2; a.w = w3;
        *(uint4*)((u16*)P.out + base) = a;
      } else {
        float* of = (float*)P.out + base;
        float4 f0 = {bf_lo(w0), bf_hi(w0), bf_lo(w1), bf_hi(w1)};
        float4 f1 = {bf_lo(w2), bf_hi(w2), bf_lo(w3), bf_hi(w3)};
        *(float4*)of = f0; *(float4*)(of+4) = f1;
      }
    }
  }

  // spill h registers to LDS for the classifier
  #pragma unroll
  for (int p = 0; p < 4; ++p){
    int idx = tid + (p << 9);
    if (idx < RPB*100){
      int r = idx / 100, j = idx - r*100;
      HF[r*108 + j] = hreg[p];
    }
  }
  __syncthreads();

  // classifier: sigmoid(relu(h@Wc1+bc1)@Wc2+bc2)
  #pragma unroll
  for (int p = 0; p < 2; ++p){
    int idx = tid + (p << 9);
    if (idx < RPB*50){
      int r = idx / 50, j = idx - r*50;
      float c = BC1[j] + dotblk(&HF[r*108], P.Wc1b, j, 50, 13);
      GXN[r*108 + j] = fmaxf(c, 0.f);
    }
  }
  __syncthreads();
  if (tid < RPB){
    float oc = loadf(P.bc2, 0, fmode);
    for (int j = 0; j < 50; ++j) oc += GXN[tid*108 + j]*WC2[j];
    float sg = fsig(oc);
    size_t off = (size_t)BSZ*YD*TT + row0 + tid;
    if (fmode == 0) ((u16*)P.out)[off] = f2bf(sg);
    else            ((float*)P.out)[off] = sg;
  }
}

extern "C" void kernel_launch(void* const* d_in, const int* in_sizes, int n_in,
                              void* d_out, int out_size, void* d_ws, size_t ws_size,
                              hipStream_t stream){
  // ws: [0..256) flags; then u16 region:
  //   Wmu1b 12800 | Wmu2b 10400 | Wc1b 5200 | fih 40960 | fhh 40960 | fl1 16384 | fl2 8192
  int* flags = (int*)d_ws;
  u16* wb = (u16*)((char*)d_ws + 256);
  u16* Wmu1b = wb;
  u16* Wmu2b = wb + 12800;
  u16* Wc1b  = wb + 23200;
  u16* fih   = wb + 28400;
  u16* fhh   = wb + 69360;
  u16* fl1   = wb + 110320;
  u16* fl2   = wb + 126704;

  detect_kernel<<<2, 256, 0, stream>>>(d_in[2], d_in[0], flags);

  WtP wp;
  wp.flags = flags;
  wp.src[0] = d_in[3];  wp.dst[0] = Wmu1b;
  wp.src[1] = d_in[5];  wp.dst[1] = Wmu2b;
  wp.src[2] = d_in[19]; wp.dst[2] = Wc1b;
  wtrans_kernel<<<24, 256, 0, stream>>>(wp);

  FrP fp;
  fp.flags = flags;
  fp.src[0] = d_in[11]; fp.dst[0] = fih;
  fp.src[1] = d_in[13]; fp.dst[1] = fhh;
  fp.src[2] = d_in[15]; fp.dst[2] = fl1;
  fp.src[3] = d_in[17]; fp.dst[3] = fl2;
  fragk<<<32, 256, 0, stream>>>(fp);

  MainP mp;
  mp.x = d_in[0]; mp.y = d_in[1]; mp.mask = d_in[2];
  mp.bmu1 = d_in[4];  mp.bmu2 = d_in[6];
  mp.bih  = d_in[12]; mp.bhh  = d_in[14];
  mp.bl1  = d_in[16]; mp.bl2  = d_in[18];
  mp.bc1  = d_in[20]; mp.bc2  = d_in[22]; mp.wc2 = d_in[21];
  mp.Wmu1b = Wmu1b; mp.Wmu2b = Wmu2b; mp.Wc1b = Wc1b;
  mp.fih = fih; mp.fhh = fhh; mp.fl1 = fl1; mp.fl2 = fl2;
  mp.flags = flags; mp.out = d_out;
  gru_main<<<NBLK, NTHR, 0, stream>>>(mp);
}

// Round 4
// 1278.989 us; speedup vs baseline: 2.2106x; 1.8824x over previous
//
#include <hip/hip_runtime.h>
#include <hip/hip_bf16.h>

// GRU_teach round 4 (resubmit; previous bench was a container/infra failure).
// Round-3 structure (8 waves, 2/SIMD) minus the spills.
// Root cause of rounds 2-3: launch_bounds(...,2) caps arch-VGPRs at 128;
// register-resident weight fragments (160-208 regs) spilled to scratch ->
// per-thread-unique reloads in the t-loop -> 3.3-6.4 GB HBM fetch.
// Fix: fit under 128. Register weights cut to 20 uint4/lane (wih/whh nt=w,w+8
// + wl1): 80 regs. nt16-18 ih/hh frags + Wl2 live in LDS (40 KB, read via
// ds_read_b128 per step, overlapped with reg-tile MFMAs). Dead nt=19 tile
// (cols 304-319 all padding) dropped. nt16-18 split: ih on waves 0-2,
// hh on waves 4-6 (was: both on waves 0-3).
// Everything else identical to round 3 (RPB=16, 256 blocks, 512 thr,
// OS slot XOR-swizzle, h in registers, 8-step y/mask windows).

#define BSZ   4096
#define XD    128
#define YD    64
#define TT    200
#define NH3   300
#define RPB   16
#define NBLK  (BSZ / RPB)
#define NTHR  512

typedef unsigned short u16;
typedef unsigned int   u32;
typedef __attribute__((ext_vector_type(8))) short s16x8;
typedef __attribute__((ext_vector_type(4))) float f32x4;

__device__ __forceinline__ float bf_lo(u32 u){ return __uint_as_float(u << 16); }
__device__ __forceinline__ float bf_hi(u32 u){ return __uint_as_float(u & 0xFFFF0000u); }
__device__ __forceinline__ u16 f2bf(float f){
  u32 u = __float_as_uint(f);
  u32 r = (u + 0x7FFFu + ((u >> 16) & 1u)) >> 16;   // RNE
  return (u16)r;
}
__device__ __forceinline__ float loadf(const void* p, size_t i, int fmode){
  return (fmode == 0) ? __uint_as_float(((u32)((const u16*)p)[i]) << 16)
                      : ((const float*)p)[i];
}
__device__ __forceinline__ float fsig(float x){ return 1.f/(1.f + __expf(-x)); }
__device__ __forceinline__ float ftanh(float x){ float e = __expf(2.f*x); return 1.f - 2.f/(e + 1.f); }

__device__ __forceinline__ f32x4 mfma16(uint4 a, uint4 b, f32x4 c){
  s16x8 as, bs;
  __builtin_memcpy(&as, &a, 16);
  __builtin_memcpy(&bs, &b, 16);
  return __builtin_amdgcn_mfma_f32_16x16x32_bf16(as, bs, c, 0, 0, 0);
}

// dot of fp32 LDS row (KB*8 floats, zero-padded) with k-blocked bf16 weights, column n of N
__device__ __forceinline__ float dotblk(const float* xr, const u16* wb, int n, int N, int KB){
  float a = 0.f;
  const uint4* wp = (const uint4*)wb;
  #pragma unroll
  for (int kb = 0; kb < KB; ++kb){
    uint4 u = wp[kb * N + n];
    const float4* xp = (const float4*)(xr + (kb << 3));
    float4 x0 = xp[0], x1 = xp[1];
    a += x0.x*bf_lo(u.x) + x0.y*bf_hi(u.x) + x0.z*bf_lo(u.y) + x0.w*bf_hi(u.y);
    a += x1.x*bf_lo(u.z) + x1.y*bf_hi(u.z) + x1.z*bf_lo(u.w) + x1.w*bf_hi(u.w);
  }
  return a;
}

// ---------------- dtype detection (unchanged, verified) ----------------
__global__ void detect_kernel(const void* mask, const void* x, int* flags){
  __shared__ int cnt[4];
  if (threadIdx.x < 4) cnt[threadIdx.x] = 0;
  __syncthreads();
  if (blockIdx.x == 0){
    const unsigned char* p = (const unsigned char*)mask;
    int c0=0, c1=0, c2=0, c3=0;
    for (int i = threadIdx.x; i < 4096; i += 256){
      unsigned char b = p[i];
      if (b == 0x3F && (i & 3) == 1) c0++;
      if (b == 0x3F && (i & 3) == 3) c1++;
      if (b == 1    && (i & 3) != 0) c2++;
      if (b == 1)                    c3++;
    }
    atomicAdd(&cnt[0], c0); atomicAdd(&cnt[1], c1);
    atomicAdd(&cnt[2], c2); atomicAdd(&cnt[3], c3);
    __syncthreads();
    if (threadIdx.x == 0){
      int mm;
      if      (cnt[0] > 0) mm = 0;
      else if (cnt[1] > 0) mm = 1;
      else if (cnt[2] > 0) mm = 3;
      else if (cnt[3] > 0) mm = 2;
      else                 mm = 0;
      flags[1] = mm;
    }
  } else {
    const u16* u = (const u16*)x;
    int c = 0;
    for (int i = threadIdx.x; i < 4096; i += 256){
      int ex = (u[i] >> 7) & 0xFF;
      if (ex >= 147) c++;
    }
    atomicAdd(&cnt[0], c);
    __syncthreads();
    if (threadIdx.x == 0) flags[0] = (cnt[0] > 32) ? 1 : 0;
  }
}

// -------- blocked repack for VALU paths (Wmu1, Wmu2, Wc1): [K][N] -> [kb][N][8] bf16 --------
struct WtP { const void* src[3]; u16* dst[3]; const int* flags; };

__global__ void wtrans_kernel(WtP a){
  const int Ks[3]  = {128, 100, 100};
  const int Ns[3]  = {100, 100,  50};
  const int KBs[3] = { 16,  13,  13};
  int m   = blockIdx.x >> 3;
  int sub = blockIdx.x & 7;
  int K = Ks[m], N = Ns[m], KB = KBs[m];
  const void* src = a.src[m];
  u16* dst = a.dst[m];
  int fmode = a.flags[0];
  int E = KB * N * 8;
  for (int e = sub*256 + threadIdx.x; e < E; e += 8*256){
    int idx = e >> 3, kc = e & 7;
    int n = idx % N, kb = idx / N;
    int k = kb*8 + kc;
    float v = (k < K) ? loadf(src, (size_t)k * N + n, fmode) : 0.f;
    dst[e] = f2bf(v);
  }
}

// -------- MFMA B-fragment repack: frag[nt][kc][lane][8] with B[k][n], n=lane&15, k=kc*32+(lane>>4)*8+j --------
struct FrP { const void* src[4]; u16* dst[4]; const int* flags; };

__global__ void fragk(FrP a){
  const int Ks[4]  = {128, 100, 100, 100};
  const int Ns[4]  = {300, 300, 100,  64};
  const int NTs[4] = { 20,  20,   8,   4};
  int m   = blockIdx.x >> 3;
  int sub = blockIdx.x & 7;
  int K = Ks[m], N = Ns[m];
  const void* src = a.src[m];
  u16* dst = a.dst[m];
  int fmode = a.flags[0];
  int E = NTs[m] * 2048;
  for (int e = sub*256 + threadIdx.x; e < E; e += 8*256){
    int j    = e & 7;
    int lane = (e >> 3) & 63;
    int kc   = (e >> 9) & 3;
    int nt   = e >> 11;
    int k = kc*32 + ((lane >> 4) << 3) + j;
    int n = nt*16 + (lane & 15);
    float v = (k < K && n < N) ? loadf(src, (size_t)k * N + n, fmode) : 0.f;
    dst[e] = f2bf(v);
  }
}

// ---------------- main persistent kernel ----------------
struct MainP {
  const void *x, *y, *mask;
  const void *bmu1, *bmu2, *bih, *bhh, *bl1, *bl2, *bc1, *bc2, *wc2;
  const u16 *Wmu1b, *Wmu2b, *Wc1b;
  const u16 *fih, *fhh, *fl1, *fl2;
  const int* flags;
  void* out;
};

// 1024 (r,d) pairs over 512 threads: 2 pairs/thread.
__device__ __forceinline__ void load_win8(const void* Y, const void* M, int row0, int t,
                                          int fmode, int mmode, uint4* yv, u32& mb){
  mb = 0u;
  #pragma unroll
  for (int p = 0; p < 2; ++p){
    int idx = threadIdx.x + (p << 9);
    int r = idx >> 6, d = idx & 63;
    size_t base = ((size_t)(row0 + r)*64 + d)*200 + t;
    uint4 yw;
    if (fmode == 0){
      yw = *(const uint4*)((const u16*)Y + base);
    } else {
      const float* yf = (const float*)Y + base;
      float4 f0 = *(const float4*)yf;
      float4 f1 = *(const float4*)(yf + 4);
      yw.x = (u32)f2bf(f0.x) | ((u32)f2bf(f0.y) << 16);
      yw.y = (u32)f2bf(f0.z) | ((u32)f2bf(f0.w) << 16);
      yw.z = (u32)f2bf(f1.x) | ((u32)f2bf(f1.y) << 16);
      yw.w = (u32)f2bf(f1.z) | ((u32)f2bf(f1.w) << 16);
    }
    yv[p] = yw;
    u32 bits = 0;
    if (mmode == 0){
      uint4 mw = *(const uint4*)((const u16*)M + base);
      u32 w0 = mw.x, w1 = mw.y, w2 = mw.z, w3 = mw.w;
      if (w0 & 0xFFFFu) bits |= 1u;  if (w0 >> 16) bits |= 2u;
      if (w1 & 0xFFFFu) bits |= 4u;  if (w1 >> 16) bits |= 8u;
      if (w2 & 0xFFFFu) bits |= 16u; if (w2 >> 16) bits |= 32u;
      if (w3 & 0xFFFFu) bits |= 64u; if (w3 >> 16) bits |= 128u;
    } else if (mmode == 1){
      const float* mf = (const float*)M + base;
      float4 f0 = *(const float4*)mf;
      float4 f1 = *(const float4*)(mf + 4);
      if (f0.x != 0.f) bits |= 1u;  if (f0.y != 0.f) bits |= 2u;
      if (f0.z != 0.f) bits |= 4u;  if (f0.w != 0.f) bits |= 8u;
      if (f1.x != 0.f) bits |= 16u; if (f1.y != 0.f) bits |= 32u;
      if (f1.z != 0.f) bits |= 64u; if (f1.w != 0.f) bits |= 128u;
    } else if (mmode == 2){
      const int* mi = (const int*)M + base;
      int4 v0 = *(const int4*)mi;
      int4 v1 = *(const int4*)(mi + 4);
      if (v0.x) bits |= 1u;  if (v0.y) bits |= 2u;
      if (v0.z) bits |= 4u;  if (v0.w) bits |= 8u;
      if (v1.x) bits |= 16u; if (v1.y) bits |= 32u;
      if (v1.z) bits |= 64u; if (v1.w) bits |= 128u;
    } else {
      uint2 u = *(const uint2*)((const unsigned char*)M + base);
      #pragma unroll
      for (int q = 0; q < 4; ++q){
        if ((u.x >> (q*8)) & 0xFFu) bits |= 1u << q;
        if ((u.y >> (q*8)) & 0xFFu) bits |= 1u << (4 + q);
      }
    }
    mb |= bits << (p << 3);
  }
}

__global__ __launch_bounds__(NTHR, 2) void gru_main(MainP P){
  __shared__ u16   XIL[RPB*136];     // x_il bf16, row stride 136
  __shared__ u16   HB [RPB*136];     // h bf16 (A operand)
  __shared__ u16   HN2[RPB*136];     // tanh(h@Wl1+bl1) bf16
  __shared__ float HF [RPB*108];     // final h fp32 (classifier only)
  __shared__ float SRZ[RPB*204];     // r|z preacts (also fp32 x staging in prologue)
  __shared__ float GXN[RPB*108];
  __shared__ float GHN[RPB*108];
  __shared__ u16   OS [RPB*64*16];   // out window: [r][d][slot], slot XOR-swizzled
  __shared__ u16   FIH2[3*4*64*8];   // ih frags nt=16..18 (LDS-resident weights)
  __shared__ u16   FHH2[3*4*64*8];   // hh frags nt=16..18
  __shared__ u16   FL2 [4*4*64*8];   // Wl2 frags nt=0..3
  __shared__ float BIH[304], BHH[304], BL1[128], BL2[64], BC1[64], WC2[64], BMU1[112], BMU2[112];

  const int tid  = threadIdx.x;
  const int row0 = blockIdx.x * RPB;
  const int fmode = P.flags[0];
  const int mmode = P.flags[1];
  const int w  = tid >> 6;           // wave 0..7
  const int ln = tid & 63;
  const int col = ln & 15;
  const int q4  = (ln >> 4) << 2;

  // y/mask windows (8 steps), 2 pairs/thread
  uint4 yc[2], yn[2];
  u32 mc, mn;
  load_win8(P.y, P.mask, row0, 0, fmode, mmode, yc, mc);
  load_win8(P.y, P.mask, row0, 8, fmode, mmode, yn, mn);

  // register weight fragments: nt = w and w+8 for ih/hh (always < 16), wl1 nt = w.
  // 20 uint4/lane = 80 VGPRs -- fits the 128 arch cap at 2 waves/SIMD.
  uint4 wih[2][4], whh[2][4], wl1[4];
  #pragma unroll
  for (int i = 0; i < 2; ++i){
    int nt = w + 8*i;
    #pragma unroll
    for (int kc = 0; kc < 4; ++kc){
      wih[i][kc] = *(const uint4*)(P.fih + (((nt*4 + kc) << 6) + ln)*8);
      whh[i][kc] = *(const uint4*)(P.fhh + (((nt*4 + kc) << 6) + ln)*8);
    }
  }
  #pragma unroll
  for (int kc = 0; kc < 4; ++kc)
    wl1[kc] = *(const uint4*)(P.fl1 + (((w*4 + kc) << 6) + ln)*8);

  // stage LDS-resident weights: fih/fhh nt 16..18 (u16 [32768,38912)), fl2 whole
  {
    const uint4* si = (const uint4*)(P.fih + 32768);
    const uint4* sh = (const uint4*)(P.fhh + 32768);
    const uint4* sl = (const uint4*)P.fl2;
    uint4* di = (uint4*)FIH2; uint4* dh = (uint4*)FHH2; uint4* dl = (uint4*)FL2;
    for (int i = tid; i < 768; i += NTHR){ di[i] = si[i]; dh[i] = sh[i]; }
    for (int i = tid; i < 1024; i += NTHR) dl[i] = sl[i];
  }

  // zero LDS
  for (int i = tid; i < RPB*136/2; i += NTHR){
    ((u32*)XIL)[i] = 0u; ((u32*)HB)[i] = 0u; ((u32*)HN2)[i] = 0u;
  }
  for (int i = tid; i < RPB*108; i += NTHR){ HF[i] = 0.f; GXN[i] = 0.f; GHN[i] = 0.f; }
  for (int i = tid; i < RPB*64*8; i += NTHR){ ((u32*)OS)[i] = 0u; }

  // biases
  for (int i = tid; i < 304; i += NTHR){
    BIH[i] = (i < 300) ? loadf(P.bih, i, fmode) : 0.f;
    BHH[i] = (i < 300) ? loadf(P.bhh, i, fmode) : 0.f;
  }
  if (tid < 128) BL1[tid] = (tid < 100) ? loadf(P.bl1, tid, fmode) : 0.f;
  if (tid < 64){
    BL2[tid] = loadf(P.bl2, tid, fmode);
    BC1[tid] = (tid < 50) ? loadf(P.bc1, tid, fmode) : 0.f;
    WC2[tid] = (tid < 50) ? loadf(P.wc2, tid, fmode) : 0.f;
  }
  if (tid < 112){
    BMU1[tid] = (tid < 100) ? loadf(P.bmu1, tid, fmode) : 0.f;
    BMU2[tid] = (tid < 100) ? loadf(P.bmu2, tid, fmode) : 0.f;
  }
  __syncthreads();

  // ---- prologue h0 = tanh(x@Wmu1+bmu1)@Wmu2+bmu2 (VALU, once) ----
  {
    int idx = tid;                   // RPB*32 == 512: single pass
    int r = idx >> 5, kq = idx & 31;
    size_t base = ((size_t)(row0 + r) << 7) + ((size_t)kq << 2);
    float v0, v1, v2, v3;
    if (fmode == 0){
      uint2 u = *(const uint2*)((const u16*)P.x + base);
      v0 = bf_lo(u.x); v1 = bf_hi(u.x); v2 = bf_lo(u.y); v3 = bf_hi(u.y);
    } else {
      float4 f = *(const float4*)((const float*)P.x + base);
      v0 = f.x; v1 = f.y; v2 = f.z; v3 = f.w;
    }
    float* dst = &SRZ[r*204 + (kq << 2)];
    dst[0] = v0; dst[1] = v1; dst[2] = v2; dst[3] = v3;
  }
  __syncthreads();
  #pragma unroll
  for (int p = 0; p < 4; ++p){
    int idx = tid + (p << 9);
    if (idx < RPB*100){
      int r = idx / 100, j = idx - r*100;
      GXN[r*108 + j] = ftanh(BMU1[j] + dotblk(&SRZ[r*204], P.Wmu1b, j, 100, 16));
    }
  }
  __syncthreads();
  float hreg[4];                      // h state in registers (map: idx=tid+512p -> (r,j))
  #pragma unroll
  for (int p = 0; p < 4; ++p){
    hreg[p] = 0.f;
    int idx = tid + (p << 9);
    if (idx < RPB*100){
      int r = idx / 100, j = idx - r*100;
      float hv = BMU2[j] + dotblk(&GXN[r*108], P.Wmu2b, j, 100, 13);
      hreg[p] = hv;
      HB[r*136 + j] = f2bf(hv);
    }
  }
  __syncthreads();

  // ---- t-loop ----
  for (int t = 0; t < TT; ++t){
    const int tc8 = t & 7;

    if (tc8 == 0 && t){
      #pragma unroll
      for (int p = 0; p < 2; ++p) yc[p] = yn[p];
      mc = mn;
      if (t + 8 < TT) load_win8(P.y, P.mask, row0, t + 8, fmode, mmode, yn, mn);
    }
    if ((t & 15) == 0 && t){
      // flush out window t-16..t-1 (un-swizzle words; full 32B per (r,d))
      int t0 = t - 16;
      const u32* ow = (const u32*)OS;
      #pragma unroll
      for (int p = 0; p < 2; ++p){
        int idx = tid + (p << 9);
        int r = idx >> 6, d = idx & 63;
        int swz = ((d >> 2) ^ r) & 7;
        int wb = idx << 3;
        u32 w0 = ow[wb + (0 ^ swz)], w1 = ow[wb + (1 ^ swz)];
        u32 w2 = ow[wb + (2 ^ swz)], w3 = ow[wb + (3 ^ swz)];
        u32 w4 = ow[wb + (4 ^ swz)], w5 = ow[wb + (5 ^ swz)];
        u32 w6 = ow[wb + (6 ^ swz)], w7 = ow[wb + (7 ^ swz)];
        size_t base = ((size_t)(row0 + r)*64 + d)*200 + t0;
        if (fmode == 0){
          u16* ob = (u16*)P.out + base;
          uint4 a; a.x = w0; a.y = w1; a.z = w2; a.w = w3;
          uint4 b; b.x = w4; b.y = w5; b.z = w6; b.w = w7;
          *(uint4*)ob = a;
          *(uint4*)(ob + 8) = b;
        } else {
          float* of = (float*)P.out + base;
          float4 f0 = {bf_lo(w0), bf_hi(w0), bf_lo(w1), bf_hi(w1)};
          float4 f1 = {bf_lo(w2), bf_hi(w2), bf_lo(w3), bf_hi(w3)};
          float4 f2 = {bf_lo(w4), bf_hi(w4), bf_lo(w5), bf_hi(w5)};
          float4 f3 = {bf_lo(w6), bf_hi(w6), bf_lo(w7), bf_hi(w7)};
          *(float4*)of = f0; *(float4*)(of+4) = f1;
          *(float4*)(of+8) = f2; *(float4*)(of+12) = f3;
        }
      }
    }

    // stage1: build x_il (teacher forcing; y_prev from bf16 out window)
    #pragma unroll
    for (int p = 0; p < 2; ++p){
      int idx = tid + (p << 9);
      int r = idx >> 6, d = idx & 63;
      u32 w01 = (tc8 & 2) ? yc[p].y : yc[p].x;
      u32 w23 = (tc8 & 2) ? yc[p].w : yc[p].z;
      u32 word = (tc8 & 4) ? w23 : w01;
      u16 yv16 = (tc8 & 1) ? (u16)(word >> 16) : (u16)(word & 0xFFFFu);
      bool mv = (mc >> ((p << 3) | tc8)) & 1u;
      int sl = ((t + 15) & 15) ^ ((((d >> 2) ^ r) & 7) << 1);
      u16 yp16 = OS[(idx << 4) + sl];
      u32 val = (u32)(mv ? yv16 : yp16) | ((mv ? 0x3F80u : 0u) << 16);
      *(u32*)(&XIL[r*136 + (d << 1)]) = val;
    }
    __syncthreads();

    // stage2: gx = x_il@Wih, gh = h@Whh
    // reg tiles nt=w, w+8; LDS tiles nt=16..18 (ih: waves 0-2, hh: waves 4-6)
    {
      uint4 xa[4], ha[4];
      #pragma unroll
      for (int kc = 0; kc < 4; ++kc){
        int ao = (ln & 15)*136 + kc*32 + ((ln >> 4) << 3);
        xa[kc] = *(const uint4*)(&XIL[ao]);
        ha[kc] = *(const uint4*)(&HB[ao]);
      }
      // issue LDS weight-frag reads early (overlap with reg-tile MFMAs)
      const int lw = w & 3;                 // 0..3
      const bool doL = lw < 3;              // waves 3,7 idle in LDS-tile phase
      const u16* lbase = (w < 4) ? FIH2 : FHH2;
      uint4 lf[4];
      if (doL){
        #pragma unroll
        for (int kc = 0; kc < 4; ++kc)
          lf[kc] = *(const uint4*)(lbase + (((lw*4 + kc) << 6) + ln)*8);
      }

      // tile A: nt = w (n < 128 always): shared acc
      {
        f32x4 ac = {0.f, 0.f, 0.f, 0.f};
        #pragma unroll
        for (int kc = 0; kc < 4; ++kc) ac = mfma16(xa[kc], wih[0][kc], ac);
        #pragma unroll
        for (int kc = 0; kc < 4; ++kc) ac = mfma16(ha[kc], whh[0][kc], ac);
        int n = w*16 + col;
        float bb = BIH[n] + BHH[n];
        #pragma unroll
        for (int reg = 0; reg < 4; ++reg)
          SRZ[(q4 + reg)*204 + n] = ac[reg] + bb;
      }
      // tile B: nt = w + 8
      if (w < 4){                           // n in [128,192): shared acc
        f32x4 ac = {0.f, 0.f, 0.f, 0.f};
        #pragma unroll
        for (int kc = 0; kc < 4; ++kc) ac = mfma16(xa[kc], wih[1][kc], ac);
        #pragma unroll
        for (int kc = 0; kc < 4; ++kc) ac = mfma16(ha[kc], whh[1][kc], ac);
        int n = (w + 8)*16 + col;
        float bb = BIH[n] + BHH[n];
        #pragma unroll
        for (int reg = 0; reg < 4; ++reg)
          SRZ[(q4 + reg)*204 + n] = ac[reg] + bb;
      } else {                              // n in [192,256): straddle/split
        f32x4 ax = {0.f,0.f,0.f,0.f}, ah = {0.f,0.f,0.f,0.f};
        #pragma unroll
        for (int kc = 0; kc < 4; ++kc){
          ax = mfma16(xa[kc], wih[1][kc], ax);
          ah = mfma16(ha[kc], whh[1][kc], ah);
        }
        int n = (w + 8)*16 + col;
        if (n < 200){
          float bb = BIH[n] + BHH[n];
          #pragma unroll
          for (int reg = 0; reg < 4; ++reg)
            SRZ[(q4 + reg)*204 + n] = ax[reg] + ah[reg] + bb;
        } else {
          float b1 = BIH[n], b2 = BHH[n];
          #pragma unroll
          for (int reg = 0; reg < 4; ++reg){
            GXN[(q4 + reg)*108 + n - 200] = ax[reg] + b1;
            GHN[(q4 + reg)*108 + n - 200] = ah[reg] + b2;
          }
        }
      }
      // LDS tile: nt = 16+lw, n in [256,304): ih-only (w<3) / hh-only (4<=w<7)
      if (doL){
        if (w < 4){
          f32x4 al = {0.f,0.f,0.f,0.f};
          #pragma unroll
          for (int kc = 0; kc < 4; ++kc) al = mfma16(xa[kc], lf[kc], al);
          int n = 256 + lw*16 + col;
          float b1 = BIH[n];
          #pragma unroll
          for (int reg = 0; reg < 4; ++reg)
            GXN[(q4 + reg)*108 + n - 200] = al[reg] + b1;
        } else {
          f32x4 al = {0.f,0.f,0.f,0.f};
          #pragma unroll
          for (int kc = 0; kc < 4; ++kc) al = mfma16(ha[kc], lf[kc], al);
          int n = 256 + lw*16 + col;
          float b2 = BHH[n];
          #pragma unroll
          for (int reg = 0; reg < 4; ++reg)
            GHN[(q4 + reg)*108 + n - 200] = al[reg] + b2;
        }
      }
    }
    __syncthreads();

    // stage3: gates + h update (h in registers)
    #pragma unroll
    for (int p = 0; p < 4; ++p){
      int idx = tid + (p << 9);
      if (idx < RPB*100){
        int r = idx / 100, j = idx - r*100;
        float rr = fsig(SRZ[r*204 + j]);
        float zz = fsig(SRZ[r*204 + 100 + j]);
        float nn = ftanh(GXN[r*108 + j] + rr*GHN[r*108 + j]);
        float hv = (1.f - zz)*nn + zz*hreg[p];
        hreg[p] = hv;
        HB[r*136 + j] = f2bf(hv);
      }
    }
    __syncthreads();

    // stage4: hn2 = tanh(h@Wl1+bl1) (MFMA, 8 tiles over 8 waves: nt = w)
    {
      uint4 ha[4];
      #pragma unroll
      for (int kc = 0; kc < 4; ++kc){
        int ao = (ln & 15)*136 + kc*32 + ((ln >> 4) << 3);
        ha[kc] = *(const uint4*)(&HB[ao]);
      }
      f32x4 ac = {0.f,0.f,0.f,0.f};
      #pragma unroll
      for (int kc = 0; kc < 4; ++kc) ac = mfma16(ha[kc], wl1[kc], ac);
      int n = w*16 + col;
      #pragma unroll
      for (int reg = 0; reg < 4; ++reg)
        HN2[(q4 + reg)*136 + n] = f2bf(ftanh(ac[reg] + BL1[n]));
    }
    __syncthreads();

    // stage5: out_t = hn2@Wl2+bl2 (MFMA, 4 tiles: waves 0..3, Wl2 from LDS)
    if (w < 4){
      uint4 na[4], lw2[4];
      #pragma unroll
      for (int kc = 0; kc < 4; ++kc){
        int ao = (ln & 15)*136 + kc*32 + ((ln >> 4) << 3);
        na[kc] = *(const uint4*)(&HN2[ao]);
        lw2[kc] = *(const uint4*)(FL2 + (((w*4 + kc) << 6) + ln)*8);
      }
      f32x4 ac = {0.f,0.f,0.f,0.f};
      #pragma unroll
      for (int kc = 0; kc < 4; ++kc) ac = mfma16(na[kc], lw2[kc], ac);
      int d = w*16 + col;
      #pragma unroll
      for (int reg = 0; reg < 4; ++reg){
        float o = ac[reg] + BL2[d];
        int rr = q4 + reg;
        int sl = (t & 15) ^ ((((d >> 2) ^ rr) & 7) << 1);
        OS[((rr*64 + d) << 4) + sl] = f2bf(o);
      }
    }
    __syncthreads();
  }

  // final flush: t = 192..199 (logical words 0..3, un-swizzled)
  {
    int t0 = TT - 8;
    const u32* ow = (const u32*)OS;
    #pragma unroll
    for (int p = 0; p < 2; ++p){
      int idx = tid + (p << 9);
      int r = idx >> 6, d = idx & 63;
      int swz = ((d >> 2) ^ r) & 7;
      int wb = idx << 3;
      u32 w0 = ow[wb + (0 ^ swz)], w1 = ow[wb + (1 ^ swz)];
      u32 w2 = ow[wb + (2 ^ swz)], w3 = ow[wb + (3 ^ swz)];
      size_t base = ((size_t)(row0 + r)*64 + d)*200 + t0;
      if (fmode == 0){
        uint4 a; a.x = w0; a.y = w1; a.z = w2; a.w = w3;
        *(uint4*)((u16*)P.out + base) = a;
      } else {
        float* of = (float*)P.out + base;
        float4 f0 = {bf_lo(w0), bf_hi(w0), bf_lo(w1), bf_hi(w1)};
        float4 f1 = {bf_lo(w2), bf_hi(w2), bf_lo(w3), bf_hi(w3)};
        *(float4*)of = f0; *(float4*)(of+4) = f1;
      }
    }
  }

  // spill h registers to LDS for the classifier
  #pragma unroll
  for (int p = 0; p < 4; ++p){
    int idx = tid + (p << 9);
    if (idx < RPB*100){
      int r = idx / 100, j = idx - r*100;
      HF[r*108 + j] = hreg[p];
    }
  }
  __syncthreads();

  // classifier: sigmoid(relu(h@Wc1+bc1)@Wc2+bc2)
  #pragma unroll
  for (int p = 0; p < 2; ++p){
    int idx = tid + (p << 9);
    if (idx < RPB*50){
      int r = idx / 50, j = idx - r*50;
      float c = BC1[j] + dotblk(&HF[r*108], P.Wc1b, j, 50, 13);
      GXN[r*108 + j] = fmaxf(c, 0.f);
    }
  }
  __syncthreads();
  if (tid < RPB){
    float oc = loadf(P.bc2, 0, fmode);
    for (int j = 0; j < 50; ++j) oc += GXN[tid*108 + j]*WC2[j];
    float sg = fsig(oc);
    size_t off = (size_t)BSZ*YD*TT + row0 + tid;
    if (fmode == 0) ((u16*)P.out)[off] = f2bf(sg);
    else            ((float*)P.out)[off] = sg;
  }
}

extern "C" void kernel_launch(void* const* d_in, const int* in_sizes, int n_in,
                              void* d_out, int out_size, void* d_ws, size_t ws_size,
                              hipStream_t stream){
  // ws: [0..256) flags; then u16 region:
  //   Wmu1b 12800 | Wmu2b 10400 | Wc1b 5200 | fih 40960 | fhh 40960 | fl1 16384 | fl2 8192
  int* flags = (int*)d_ws;
  u16* wb = (u16*)((char*)d_ws + 256);
  u16* Wmu1b = wb;
  u16* Wmu2b = wb + 12800;
  u16* Wc1b  = wb + 23200;
  u16* fih   = wb + 28400;
  u16* fhh   = wb + 69360;
  u16* fl1   = wb + 110320;
  u16* fl2   = wb + 126704;

  detect_kernel<<<2, 256, 0, stream>>>(d_in[2], d_in[0], flags);

  WtP wp;
  wp.flags = flags;
  wp.src[0] = d_in[3];  wp.dst[0] = Wmu1b;
  wp.src[1] = d_in[5];  wp.dst[1] = Wmu2b;
  wp.src[2] = d_in[19]; wp.dst[2] = Wc1b;
  wtrans_kernel<<<24, 256, 0, stream>>>(wp);

  FrP fp;
  fp.flags = flags;
  fp.src[0] = d_in[11]; fp.dst[0] = fih;
  fp.src[1] = d_in[13]; fp.dst[1] = fhh;
  fp.src[2] = d_in[15]; fp.dst[2] = fl1;
  fp.src[3] = d_in[17]; fp.dst[3] = fl2;
  fragk<<<32, 256, 0, stream>>>(fp);

  MainP mp;
  mp.x = d_in[0]; mp.y = d_in[1]; mp.mask = d_in[2];
  mp.bmu1 = d_in[4];  mp.bmu2 = d_in[6];
  mp.bih  = d_in[12]; mp.bhh  = d_in[14];
  mp.bl1  = d_in[16]; mp.bl2  = d_in[18];
  mp.bc1  = d_in[20]; mp.bc2  = d_in[22]; mp.wc2 = d_in[21];
  mp.Wmu1b = Wmu1b; mp.Wmu2b = Wmu2b; mp.Wc1b = Wc1b;
  mp.fih = fih; mp.fhh = fhh; mp.fl1 = fl1; mp.fl2 = fl2;
  mp.flags = flags; mp.out = d_out;
  gru_main<<<NBLK, NTHR, 0, stream>>>(mp);
}